// Round 1
// baseline (333.675 us; speedup 1.0000x reference)
//
#include <hip/hip_runtime.h>
#include <hip/hip_bf16.h>
#include <math.h>

typedef __attribute__((ext_vector_type(4))) float f32x4;
typedef __attribute__((ext_vector_type(8))) __bf16 bf16x8;

#define HLEN 200

// 512 threads = 8 waves. Waves 0-3 own batch row 2b, waves 4-7 own row 2b+1.
// Both groups share one LDS copy of W1/Wr1 (staged in MFMA-fragment order).
// LDS ~75 KB -> 2 blocks/CU; 2 blocks x 8 waves = 16 waves/CU (~50% occ),
// double the previous 8 waves/CU. VGPR capped at 128 via launch_bounds(512,4).
__global__ __launch_bounds__(512, 4)
void nais_main(const int* __restrict__ history, const int* __restrict__ target,
               const int* __restrict__ hist_region, const int* __restrict__ tgt_region,
               const float* __restrict__ tgt_dist,
               const float* __restrict__ emb_hist, const float* __restrict__ emb_tgt,
               const float* __restrict__ emb_region, const float* __restrict__ emb_dist,
               const float* __restrict__ W1, const float* __restrict__ b1, const float* __restrict__ w2,
               const float* __restrict__ Wr1, const float* __restrict__ br1, const float* __restrict__ wr2,
               float* __restrict__ out)
{
  // W in MFMA B-fragment order: chunk c = ((ks*8+nt)*16+r)*4+g holds
  // W[nt*16+r][ks*32+g*8 .. +7] as bf16x8. A wave's 64 ds_read_b128 for fixed
  // (ks,nt) cover 1024 contiguous bytes, one distinct 16B slot per lane ->
  // bank-conflict-free (replaces the 8-way-conflicting [128][136] layout).
  __shared__ __align__(16) __bf16 w1f[16384];
  __shared__ __align__(16) __bf16 wr1f[16384];
  __shared__ __align__(16) float tvec[2][128];
  __shared__ __align__(16) float trvec[2][128];
  __shared__ float b1s[128], w2s[128], br1s[128], wr2s[128];
  __shared__ float aA[2][208], aR[2][208], dAl[2][208], dRl[2][208];
  __shared__ float Ssum;
  __shared__ float red[2][4][4];

  const int tid  = threadIdx.x;
  const int lane = tid & 63;
  const int wid  = tid >> 6;     // 0..7
  const int grp  = wid >> 2;     // which batch row this half-block owns
  const int wg   = wid & 3;      // wave within group
  const int ltid = tid & 255;    // thread id within group
  const int r    = lane & 15;    // row (A) / col (B) within 16-tile
  const int g    = lane >> 4;    // k-group 0..3

  const int b = blockIdx.x * 2 + grp;

  // S = sum(embed_distance[0][:]) — wave 0 only, both groups read after sync
  if (wid == 0) {
    float s = emb_dist[lane] + emb_dist[lane + 64];
    #pragma unroll
    for (int m = 32; m >= 1; m >>= 1) s += __shfl_xor(s, m);
    if (lane == 0) Ssum = s;
  }
  if (tid < 128) { b1s[tid] = b1[tid]; w2s[tid] = w2[tid]; br1s[tid] = br1[tid]; wr2s[tid] = wr2[tid]; }
  if (ltid < 128) {
    tvec[grp][ltid]  = emb_tgt[(long)target[b] * 128 + ltid];
    trvec[grp][ltid] = emb_region[(long)tgt_region[b] * 128 + ltid];
  }

  // stage W1/Wr1 as bf16 fragments into LDS (once per block, shared by both rows)
  for (int i = tid; i < 2048; i += 512) {
    const int gg = i & 3, rr = (i >> 2) & 15, nt = (i >> 6) & 7, ks = i >> 9;
    const int n = nt * 16 + rr, d0 = ks * 32 + gg * 8;
    f32x4 v0 = *(const f32x4*)(W1  + n * 128 + d0);
    f32x4 v1 = *(const f32x4*)(W1  + n * 128 + d0 + 4);
    f32x4 u0 = *(const f32x4*)(Wr1 + n * 128 + d0);
    f32x4 u1 = *(const f32x4*)(Wr1 + n * 128 + d0 + 4);
    bf16x8 p, q;
    p[0] = (__bf16)v0.x; p[1] = (__bf16)v0.y; p[2] = (__bf16)v0.z; p[3] = (__bf16)v0.w;
    p[4] = (__bf16)v1.x; p[5] = (__bf16)v1.y; p[6] = (__bf16)v1.z; p[7] = (__bf16)v1.w;
    q[0] = (__bf16)u0.x; q[1] = (__bf16)u0.y; q[2] = (__bf16)u0.z; q[3] = (__bf16)u0.w;
    q[4] = (__bf16)u1.x; q[5] = (__bf16)u1.y; q[6] = (__bf16)u1.z; q[7] = (__bf16)u1.w;
    *(bf16x8*)&w1f[i * 8]  = p;
    *(bf16x8*)&wr1f[i * 8] = q;
  }
  __syncthreads();

  // branch worker: one 16-row M-tile GEMM [16x128]x[128x128] + relu/w2 row-reduce
  auto run_branch = [&](const float* __restrict__ grow, const float* tv,
                        const __bf16* __restrict__ Wf, const float* bs, const float* wv2,
                        float* a_arr, float* d_arr,
                        float vmask, int h, bool valid, int mt) {
    bf16x8 fr[4];
    float dot = 0.f;
    #pragma unroll
    for (int ks = 0; ks < 4; ++ks) {
      const int d0 = ks * 32 + g * 8;
      f32x4 x0 = *(const f32x4*)(grow + d0);
      f32x4 x1 = *(const f32x4*)(grow + d0 + 4);
      f32x4 t0 = *(const f32x4*)(tv + d0);
      f32x4 t1 = *(const f32x4*)(tv + d0 + 4);
      f32x4 q0 = x0 * t0 * vmask;
      f32x4 q1 = x1 * t1 * vmask;
      dot += ((q0.x + q0.y) + (q0.z + q0.w)) + ((q1.x + q1.y) + (q1.z + q1.w));
      bf16x8 fv;
      fv[0] = (__bf16)q0.x; fv[1] = (__bf16)q0.y; fv[2] = (__bf16)q0.z; fv[3] = (__bf16)q0.w;
      fv[4] = (__bf16)q1.x; fv[5] = (__bf16)q1.y; fv[6] = (__bf16)q1.z; fv[7] = (__bf16)q1.w;
      fr[ks] = fv;
    }
    // dot(h,t): lane covers 32 d's; combine the 4 k-groups sharing row r
    float df = dot;
    df += __shfl_xor(df, 16);
    df += __shfl_xor(df, 32);
    if (g == 0 && valid) d_arr[h] = df;

    f32x4 acc[8];
    #pragma unroll
    for (int nt = 0; nt < 8; ++nt) acc[nt] = (f32x4){0.f, 0.f, 0.f, 0.f};
    #pragma unroll
    for (int ks = 0; ks < 4; ++ks) {
      #pragma unroll
      for (int nt = 0; nt < 8; ++nt) {
        bf16x8 bf = *(const bf16x8*)&Wf[((ks * 8 + nt) * 64 + r * 4 + g) * 8];
        acc[nt] = __builtin_amdgcn_mfma_f32_16x16x32_bf16(fr[ks], bf, acc[nt], 0, 0, 0);
      }
    }
    // a[m] = sum_n relu(Y[m][n]+b[n])*w2[n]; lane holds col n=nt*16+r, rows g*4+q
    float s0 = 0.f, s1 = 0.f, s2 = 0.f, s3 = 0.f;
    #pragma unroll
    for (int nt = 0; nt < 8; ++nt) {
      const int n = nt * 16 + r;
      const float bias = bs[n], wv = wv2[n];
      s0 += fmaxf(acc[nt].x + bias, 0.f) * wv;
      s1 += fmaxf(acc[nt].y + bias, 0.f) * wv;
      s2 += fmaxf(acc[nt].z + bias, 0.f) * wv;
      s3 += fmaxf(acc[nt].w + bias, 0.f) * wv;
    }
    #pragma unroll
    for (int m = 1; m <= 8; m <<= 1) {
      s0 += __shfl_xor(s0, m); s1 += __shfl_xor(s1, m);
      s2 += __shfl_xor(s2, m); s3 += __shfl_xor(s3, m);
    }
    if (r == 0) {
      const int base = mt * 16 + g * 4;
      a_arr[base + 0] = s0; a_arr[base + 1] = s1;
      a_arr[base + 2] = s2; a_arr[base + 3] = s3;
    }
  };

  // 13 M-tiles (208 rows >= HLEN) split over the group's 4 waves
  for (int mt = wg; mt < 13; mt += 4) {
    const int h = mt * 16 + r;
    const bool valid = (h < HLEN);
    const float vmask = valid ? 1.f : 0.f;
    const int ia = valid ? history[b * HLEN + h] : 0;
    const int ir = valid ? hist_region[b * HLEN + h] : 0;
    const float* rowA = emb_hist + (long)ia * 128;
    const float* rowR = emb_region + (long)ir * 128;
    run_branch(rowA, tvec[grp],  w1f,  b1s, w2s,  aA[grp], dAl[grp], vmask, h, valid, mt);
    run_branch(rowR, trvec[grp], wr1f, br1s, wr2s, aR[grp], dRl[grp], vmask, h, valid, mt);
  }

  __syncthreads();
  // final: exp/mask, 4 simultaneous sums per group, beta=0.5 norm, sigmoid
  float eA = 0.f, eR = 0.f, pA = 0.f, pR = 0.f;
  const int tb = target[b];
  if (ltid < HLEN) {
    const float dv = tgt_dist[b * HLEN + ltid] * Ssum;
    const float msk = (history[b * HLEN + ltid] != tb) ? 1.f : 0.f;
    const float ea = msk * expf(aA[grp][ltid] + dv);
    const float er = msk * expf(aR[grp][ltid] + dv);
    eA = ea; eR = er;
    pA = ea * dAl[grp][ltid]; pR = er * dRl[grp][ltid];
  }
  #pragma unroll
  for (int m = 1; m <= 32; m <<= 1) {
    eA += __shfl_xor(eA, m); eR += __shfl_xor(eR, m);
    pA += __shfl_xor(pA, m); pR += __shfl_xor(pR, m);
  }
  if (lane == 0) { red[grp][wg][0] = eA; red[grp][wg][1] = eR; red[grp][wg][2] = pA; red[grp][wg][3] = pR; }
  __syncthreads();
  if (ltid == 0) {
    const float SA = red[grp][0][0] + red[grp][1][0] + red[grp][2][0] + red[grp][3][0];
    const float SR = red[grp][0][1] + red[grp][1][1] + red[grp][2][1] + red[grp][3][1];
    const float PA = red[grp][0][2] + red[grp][1][2] + red[grp][2][2] + red[grp][3][2];
    const float PR = red[grp][0][3] + red[grp][1][3] + red[grp][2][3] + red[grp][3][3];
    const float pred = PA / sqrtf(SA) + PR / sqrtf(SR);
    out[b] = 1.f / (1.f + expf(-pred));
  }
}

extern "C" void kernel_launch(void* const* d_in, const int* in_sizes, int n_in,
                              void* d_out, int out_size, void* d_ws, size_t ws_size,
                              hipStream_t stream) {
  const int*   history     = (const int*)d_in[0];
  const int*   target      = (const int*)d_in[1];
  const int*   hist_region = (const int*)d_in[2];
  const int*   tgt_region  = (const int*)d_in[3];
  const float* tgt_dist    = (const float*)d_in[4];
  const float* emb_hist    = (const float*)d_in[5];
  const float* emb_tgt     = (const float*)d_in[6];
  const float* emb_region  = (const float*)d_in[7];
  const float* emb_dist    = (const float*)d_in[8];
  const float* W1  = (const float*)d_in[9];
  const float* b1  = (const float*)d_in[10];
  const float* w2  = (const float*)d_in[11];
  const float* Wr1 = (const float*)d_in[12];
  const float* br1 = (const float*)d_in[13];
  const float* wr2 = (const float*)d_in[14];
  float* out = (float*)d_out;

  const int B = in_sizes[1];       // 1024
  dim3 grid(B / 2), block(512);
  hipLaunchKernelGGL(nais_main, grid, block, 0, stream,
                     history, target, hist_region, tgt_region, tgt_dist,
                     emb_hist, emb_tgt, emb_region, emb_dist,
                     W1, b1, w2, Wr1, br1, wr2, out);
}

// Round 2
// 108.127 us; speedup vs baseline: 3.0860x; 3.0860x over previous
//
#include <hip/hip_runtime.h>
#include <hip/hip_bf16.h>
#include <math.h>

typedef __attribute__((ext_vector_type(4))) float f32x4;
typedef __attribute__((ext_vector_type(8))) __bf16 bf16x8;

#define HLEN 200

// ---------------------------------------------------------------------------
// prep kernel: convert W1/Wr1 (f32 [128][128]) into bf16 MFMA B-fragments in
// the workspace, and compute Ssum = sum(embed_distance[0][:]).
// Fragment table layout: frag f = (nt*4+ks)*64 + lane holds
// W[n=nt*16+(lane&15)][d0=ks*32+(lane>>4)*8 .. +7] as bf16x8.
// W1 frags at ws[0..16383], Wr1 frags at ws[16384..32767] (bf16 units).
// ---------------------------------------------------------------------------
__global__ __launch_bounds__(256)
void nais_prep(const float* __restrict__ W1, const float* __restrict__ Wr1,
               const float* __restrict__ emb_dist,
               __bf16* __restrict__ wfrag, float* __restrict__ Ssum)
{
  const int id = blockIdx.x * 256 + threadIdx.x;
  if (blockIdx.x < 16) {
    const float* W = (id < 2048) ? W1 : Wr1;
    const int f    = id & 2047;
    const int lane = f & 63;
    const int ks   = (f >> 6) & 3;
    const int nt   = f >> 8;
    const int n  = nt * 16 + (lane & 15);
    const int d0 = ks * 32 + (lane >> 4) * 8;
    const float* src = W + n * 128 + d0;
    bf16x8 p;
    #pragma unroll
    for (int e = 0; e < 8; ++e) p[e] = (__bf16)src[e];
    *(bf16x8*)&wfrag[(size_t)id * 8] = p;
  } else if (threadIdx.x < 64) {
    float s = emb_dist[threadIdx.x] + emb_dist[threadIdx.x + 64];
    #pragma unroll
    for (int m = 32; m >= 1; m >>= 1) s += __shfl_xor(s, m);
    if (threadIdx.x == 0) Ssum[0] = s;
  }
}

// ---------------------------------------------------------------------------
// main kernel: 256 threads = 4 waves, ONE batch row per block, grid = B = 1024
// (exactly 4 blocks/CU). Wave role = (branch, N-half):
//   wid 0: item branch,  cols   0..63   | wid 1: item branch,  cols  64..127
//   wid 2: region branch, cols  0..63   | wid 3: region branch, cols 64..127
// W fragments live in 64 VGPRs per wave (no LDS W copy -> LDS ~6 KB).
// launch_bounds(256,4): VGPR<=128 -> 4 waves/EU -> 16 waves/CU (~50% occ).
// ---------------------------------------------------------------------------
__global__ __launch_bounds__(256, 4)
void nais_main(const int* __restrict__ history, const int* __restrict__ target,
               const int* __restrict__ hist_region, const int* __restrict__ tgt_region,
               const float* __restrict__ tgt_dist,
               const float* __restrict__ emb_hist, const float* __restrict__ emb_tgt,
               const float* __restrict__ emb_region,
               const float* __restrict__ b1, const float* __restrict__ w2,
               const float* __restrict__ br1, const float* __restrict__ wr2,
               const __bf16* __restrict__ wfrag, const float* __restrict__ SsumPtr,
               float* __restrict__ out)
{
  __shared__ __align__(16) float tvec[128];
  __shared__ __align__(16) float trvec[128];
  __shared__ float apart[4][208];   // rows 0,1: item-branch partials; 2,3: region
  __shared__ float dAl[208], dRl[208];
  __shared__ float red[4][4];

  const int tid  = threadIdx.x;
  const int lane = tid & 63;
  const int wid  = tid >> 6;
  const int r    = lane & 15;   // M-row (A) / N-col (B) within 16-tile
  const int g    = lane >> 4;   // k-group 0..3
  const int b    = blockIdx.x;
  const int br   = wid >> 1;    // 0 = item branch, 1 = region branch
  const int half = wid & 1;     // which 64-column half

  if (tid < 128) {
    tvec[tid]  = emb_tgt[(long)target[b] * 128 + tid];
    trvec[tid] = emb_region[(long)tgt_region[b] * 128 + tid];
  }

  // wave-uniform branch state
  const float* table  = br ? emb_region  : emb_hist;
  const int*   idxarr = br ? hist_region : history;
  const float* bsrc   = br ? br1 : b1;
  const float* wsrc   = br ? wr2 : w2;
  const float* tv     = br ? trvec : tvec;
  float*       dl     = br ? dRl : dAl;

  // load this wave's 16 W fragments (64 VGPRs) + bias/w2 scalars
  bf16x8 wf[4][4];
  float bias[4], wv[4];
  #pragma unroll
  for (int j = 0; j < 4; ++j) {
    const int nt = half * 4 + j;
    bias[j] = bsrc[nt * 16 + r];
    wv[j]   = wsrc[nt * 16 + r];
    #pragma unroll
    for (int ks = 0; ks < 4; ++ks)
      wf[j][ks] = *(const bf16x8*)&wfrag[(size_t)br * 16384 + ((nt * 4 + ks) * 64 + lane) * 8];
  }
  __syncthreads();   // tvec/trvec ready

  for (int mt = 0; mt < 13; ++mt) {
    const int h = mt * 16 + r;
    const bool valid = (h < HLEN);
    const int idx = valid ? idxarr[b * HLEN + h] : 0;
    const float* row = table + (long)idx * 128;

    f32x4 acc[4];
    #pragma unroll
    for (int j = 0; j < 4; ++j) acc[j] = (f32x4){0.f, 0.f, 0.f, 0.f};
    float dot = 0.f;

    #pragma unroll
    for (int ks = 0; ks < 4; ++ks) {
      const int d0 = ks * 32 + g * 8;
      f32x4 x0 = *(const f32x4*)(row + d0);
      f32x4 x1 = *(const f32x4*)(row + d0 + 4);
      f32x4 t0 = *(const f32x4*)(tv + d0);
      f32x4 t1 = *(const f32x4*)(tv + d0 + 4);
      f32x4 q0 = x0 * t0;
      f32x4 q1 = x1 * t1;
      dot += ((q0.x + q0.y) + (q0.z + q0.w)) + ((q1.x + q1.y) + (q1.z + q1.w));
      bf16x8 fv;
      fv[0] = (__bf16)q0.x; fv[1] = (__bf16)q0.y; fv[2] = (__bf16)q0.z; fv[3] = (__bf16)q0.w;
      fv[4] = (__bf16)q1.x; fv[5] = (__bf16)q1.y; fv[6] = (__bf16)q1.z; fv[7] = (__bf16)q1.w;
      #pragma unroll
      for (int j = 0; j < 4; ++j)
        acc[j] = __builtin_amdgcn_mfma_f32_16x16x32_bf16(fv, wf[j][ks], acc[j], 0, 0, 0);
    }

    // dot(h_row, t): combine the 4 k-groups sharing row r; one wave per branch writes
    float df = dot;
    df += __shfl_xor(df, 16);
    df += __shfl_xor(df, 32);
    if (half == 0 && g == 0 && valid) dl[h] = df;

    // partial a[m] over this wave's 64 columns
    float s0 = 0.f, s1 = 0.f, s2 = 0.f, s3 = 0.f;
    #pragma unroll
    for (int j = 0; j < 4; ++j) {
      s0 += fmaxf(acc[j].x + bias[j], 0.f) * wv[j];
      s1 += fmaxf(acc[j].y + bias[j], 0.f) * wv[j];
      s2 += fmaxf(acc[j].z + bias[j], 0.f) * wv[j];
      s3 += fmaxf(acc[j].w + bias[j], 0.f) * wv[j];
    }
    #pragma unroll
    for (int m = 1; m <= 8; m <<= 1) {
      s0 += __shfl_xor(s0, m); s1 += __shfl_xor(s1, m);
      s2 += __shfl_xor(s2, m); s3 += __shfl_xor(s3, m);
    }
    if (r == 0) {
      const int base = mt * 16 + g * 4;
      apart[wid][base + 0] = s0; apart[wid][base + 1] = s1;
      apart[wid][base + 2] = s2; apart[wid][base + 3] = s3;
    }
  }

  __syncthreads();
  // epilogue: exp/mask, 4 simultaneous block sums, beta=0.5 norm, sigmoid
  float eA = 0.f, eR = 0.f, pA = 0.f, pR = 0.f;
  if (tid < HLEN) {
    const float dv  = tgt_dist[b * HLEN + tid] * SsumPtr[0];
    const int   tb  = target[b];
    const float msk = (history[b * HLEN + tid] != tb) ? 1.f : 0.f;
    const float aAv = apart[0][tid] + apart[1][tid];
    const float aRv = apart[2][tid] + apart[3][tid];
    const float ea = msk * expf(aAv + dv);
    const float er = msk * expf(aRv + dv);
    eA = ea; eR = er;
    pA = ea * dAl[tid]; pR = er * dRl[tid];
  }
  #pragma unroll
  for (int m = 1; m <= 32; m <<= 1) {
    eA += __shfl_xor(eA, m); eR += __shfl_xor(eR, m);
    pA += __shfl_xor(pA, m); pR += __shfl_xor(pR, m);
  }
  if (lane == 0) { red[wid][0] = eA; red[wid][1] = eR; red[wid][2] = pA; red[wid][3] = pR; }
  __syncthreads();
  if (tid == 0) {
    const float SA = red[0][0] + red[1][0] + red[2][0] + red[3][0];
    const float SR = red[0][1] + red[1][1] + red[2][1] + red[3][1];
    const float PA = red[0][2] + red[1][2] + red[2][2] + red[3][2];
    const float PR = red[0][3] + red[1][3] + red[2][3] + red[3][3];
    const float pred = PA / sqrtf(SA) + PR / sqrtf(SR);
    out[b] = 1.f / (1.f + expf(-pred));
  }
}

extern "C" void kernel_launch(void* const* d_in, const int* in_sizes, int n_in,
                              void* d_out, int out_size, void* d_ws, size_t ws_size,
                              hipStream_t stream) {
  const int*   history     = (const int*)d_in[0];
  const int*   target      = (const int*)d_in[1];
  const int*   hist_region = (const int*)d_in[2];
  const int*   tgt_region  = (const int*)d_in[3];
  const float* tgt_dist    = (const float*)d_in[4];
  const float* emb_hist    = (const float*)d_in[5];
  const float* emb_tgt     = (const float*)d_in[6];
  const float* emb_region  = (const float*)d_in[7];
  const float* emb_dist    = (const float*)d_in[8];
  const float* W1  = (const float*)d_in[9];
  const float* b1  = (const float*)d_in[10];
  const float* w2  = (const float*)d_in[11];
  const float* Wr1 = (const float*)d_in[12];
  const float* br1 = (const float*)d_in[13];
  const float* wr2 = (const float*)d_in[14];
  float* out = (float*)d_out;

  __bf16* wfrag = (__bf16*)d_ws;                       // 32768 bf16 = 64 KB
  float*  Sp    = (float*)((char*)d_ws + 65536);       // +4 B

  const int B = in_sizes[1];       // 1024
  hipLaunchKernelGGL(nais_prep, dim3(17), dim3(256), 0, stream,
                     W1, Wr1, emb_dist, wfrag, Sp);
  hipLaunchKernelGGL(nais_main, dim3(B), dim3(256), 0, stream,
                     history, target, hist_region, tgt_region, tgt_dist,
                     emb_hist, emb_tgt, emb_region,
                     b1, w2, br1, wr2, wfrag, Sp, out);
}